// Round 6
// baseline (566.591 us; speedup 1.0000x reference)
//
#include <hip/hip_runtime.h>
#include <utility>
#include <cstddef>

// ---------------- compile-time Ivanic-Ruedenberg tables ----------------

struct Term { int o; int r; int a; float c; };
struct LTable { int n; Term t[1024]; };

constexpr double csqrt(double x) {
    if (x <= 0.0) return 0.0;
    double g = x < 1.0 ? 1.0 : x;
    for (int i = 0; i < 50; ++i) g = 0.5 * (g + x / g);
    return g;
}
constexpr int cabs_i(int x) { return x < 0 ? -x : x; }
constexpr int cmax_i(int a, int b) { return a > b ? a : b; }

constexpr void add_p(LTable& T, int o, double scale, int i, int a, int b, int l) {
    int lp = l - 1;
    int np = 2 * lp + 1;
    int row = i + 1;
    if (b == l) {
        T.t[T.n++] = Term{o, row * 3 + 2, (a + lp) * np + 2 * lp, (float)scale};
        T.t[T.n++] = Term{o, row * 3 + 0, (a + lp) * np + 0,      (float)(-scale)};
    } else if (b == -l) {
        T.t[T.n++] = Term{o, row * 3 + 2, (a + lp) * np + 0,      (float)scale};
        T.t[T.n++] = Term{o, row * 3 + 0, (a + lp) * np + 2 * lp, (float)scale};
    } else {
        T.t[T.n++] = Term{o, row * 3 + 1, (a + lp) * np + (b + lp), (float)scale};
    }
}

constexpr LTable ru_table(int l) {
    LTable T{};
    int n = 2 * l + 1;
    for (int m = -l; m <= l; ++m) {
        for (int mp = -l; mp <= l; ++mp) {
            double denom = (cabs_i(mp) == l) ? (double)((2 * l) * (2 * l - 1))
                                             : (double)((l + mp) * (l - mp));
            double d0 = (m == 0) ? 1.0 : 0.0;
            double u = csqrt((double)((l + m) * (l - m)) / denom);
            double v = 0.5 * csqrt((1.0 + d0) * (l + cabs_i(m) - 1) * (l + cabs_i(m)) / denom)
                       * (1.0 - 2.0 * d0);
            double w = -0.5 * csqrt((double)cmax_i(l - cabs_i(m) - 1, 0) * (l - cabs_i(m)) / denom)
                       * (1.0 - d0);
            int o = (m + l) * n + (mp + l);
            if (u != 0.0) add_p(T, o, u, 0, m, mp, l);
            if (v != 0.0) {
                if (m == 0) {
                    add_p(T, o, v, 1, 1, mp, l);
                    add_p(T, o, v, -1, -1, mp, l);
                } else if (m > 0) {
                    double s = (m == 1) ? csqrt(2.0) : 1.0;
                    add_p(T, o, v * s, 1, m - 1, mp, l);
                    if (m != 1) add_p(T, o, -v, -1, -m + 1, mp, l);
                } else {
                    if (m != -1) add_p(T, o, v, 1, m + 1, mp, l);
                    double s = (m == -1) ? csqrt(2.0) : 1.0;
                    add_p(T, o, v * s, -1, -m - 1, mp, l);
                }
            }
            if (w != 0.0) {
                if (m > 0) {
                    add_p(T, o, w, 1, m + 1, mp, l);
                    add_p(T, o, w, -1, -m - 1, mp, l);
                } else {
                    add_p(T, o, w, 1, m - 1, mp, l);
                    add_p(T, o, -w, -1, -m + 1, mp, l);
                }
            }
        }
    }
    return T;
}

inline constexpr LTable T2 = ru_table(2);
inline constexpr LTable T3 = ru_table(3);
inline constexpr LTable T4 = ru_table(4);

// terms for a given output entry are contiguous by construction (m-major, mp-minor)
template<const LTable& T>
constexpr int er_start(int e) {
    for (int i = 0; i < T.n; ++i) if (T.t[i].o == e) return i;
    return 0;
}
template<const LTable& T>
constexpr int er_cnt(int e) {
    int c = 0;
    for (int i = 0; i < T.n; ++i) if (T.t[i].o == e) ++c;
    return c;
}

template<const LTable& T, int S, size_t... K>
__device__ __forceinline__ float sum_terms(const float* __restrict__ R1,
                                           const float* __restrict__ P,
                                           std::index_sequence<K...>) {
    float a = 0.0f;
    ((a = fmaf(T.t[S + (int)K].c, R1[T.t[S + (int)K].r] * P[T.t[S + (int)K].a], a)), ...);
    return a;
}

// compute one entry of block l, optionally keep in array, stream ds_write to row
template<const LTable& T, int l, bool KEEP, int e>
__device__ __forceinline__ void level_one(const float* __restrict__ R1,
                                          const float* __restrict__ P,
                                          float* __restrict__ keep,
                                          float* __restrict__ row) {
    constexpr int S = er_start<T>(e);
    constexpr int C = er_cnt<T>(e);
    float v = sum_terms<T, S>(R1, P, std::make_index_sequence<C>{});
    if constexpr (KEEP) keep[e] = v;
    constexpr int d = 2 * l + 1;
    constexpr int r = e / d, c = e % d;
    constexpr int E625 = (l * l + r) * 25 + (l * l + c);  // ds_write imm offset
    row[E625] = v;
}

template<const LTable& T, int l, bool KEEP, size_t... E>
__device__ __forceinline__ void level(const float* __restrict__ R1,
                                      const float* __restrict__ P,
                                      float* __restrict__ keep,
                                      float* __restrict__ row,
                                      std::index_sequence<E...>) {
    (level_one<T, l, KEEP, (int)E>(R1, P, keep, row), ...);
}

template<size_t... E>
__device__ __forceinline__ void write_l1(const float* __restrict__ D1,
                                         float* __restrict__ row,
                                         std::index_sequence<E...>) {
    ((row[(1 + (int)E / 3) * 25 + (1 + (int)E % 3)] = D1[E]), ...);
}

typedef float v4f __attribute__((ext_vector_type(4)));

// ---------------- light barrier ----------------
// lgkm-only drain + raw s_barrier: LDS ordering only; in-flight HBM stores
// are never drained at chunk boundaries (neutral vs __syncthreads per R4 A/B,
// and required here so stores keep flowing across phases).
__device__ __forceinline__ void bar_lgkm() {
    asm volatile("s_waitcnt lgkmcnt(0)" ::: "memory");
    __builtin_amdgcn_s_barrier();
    asm volatile("" ::: "memory");
}

// ---------------- fused kernel ----------------
// Round-6 structure: INTRA-BLOCK SCATTER||COPY DOUBLE-BUFFER.
// Falsified so far: compute-lane parallelism (R1), barrier vmcnt drain (R4),
// NT-vs-L2 store path (R5). Remaining theory: the scatter->bar->copy->bar
// convoy leaves the store pipe idle during every scatter phase (all pipes
// <25% busy; wigner ~219us vs 80us write floor).
//
// Block: 256 threads = 4 waves = 256 points, 8 chunks of 32 points.
// TWO 32x625 images (2 x 80,000 B = 160,000 B LDS -> 1 block/CU,
// __launch_bounds__(256,1): VGPR-unconstrained, no spill risk).
// Iteration c: wave (c>>1) scatters chunk c into buf[c&1] (owning half-wave
// recomputes D from 4 trig regs, compile-time-immediate ds_writes,
// bank=(17*p0+E)%32 conflict-free) WHILE the other 3 waves (192 threads)
// copy chunk c-1 from buf[(c-1)&1] as a contiguous 16B v4f stream.
// One lgkm-barrier per iteration. Final chunk copied by all 256 threads.
// Buffers are disjoint per phase; the WAR on buf[c&1] (copied in phase c-1,
// overwritten in phase c) is closed by the lgkmcnt(0) drain at each barrier.

__global__ __launch_bounds__(256, 1)
void wigner_fused_kernel(const float* __restrict__ xyz, float* __restrict__ out, int Ntot) {
    __shared__ float buf[2][32 * 625];   // 160,000 B

    const int t = threadIdx.x;
    const int w = t >> 6;
    const int lane = t & 63;
    const int p0 = t & 31;
    const int gp = blockIdx.x * 256 + t;

    float x = 0.0f, y = 0.0f, z = 1.0f;
    if (gp < Ntot) {
        x = xyz[3 * gp + 0];
        y = xyz[3 * gp + 1];
        z = xyz[3 * gp + 2];
    }

    // trig without trig: ct = vz (clipped), st = sqrt(1-ct^2), cp/sp from x,y
    const float r2 = x * x + y * y + z * z;
    const float rinv = rsqrtf(fmaxf(r2, 1e-24f));
    const float ct = fminf(fmaxf(z * rinv, -1.0f), 1.0f);
    const float st = sqrtf(fmaxf(1.0f - ct * ct, 0.0f));
    const float rxy2 = x * x + y * y;
    float cp = 1.0f, sp = 0.0f;
    if (rxy2 > 0.0f) {
        const float ri = rsqrtf(rxy2);
        cp = x * ri;
        sp = y * ri;
    }
    // only ct, st, cp, sp stay live across the chunk loop

    // zero both images once (zero-structure slots never rewritten)
    {
        v4f* b4 = (v4f*)&buf[0][0];
        const v4f z4 = {0.0f, 0.0f, 0.0f, 0.0f};
#pragma unroll 4
        for (int k = t; k < 10000; k += 256) b4[k] = z4;
    }
    bar_lgkm();

    const long long blk_f = (long long)blockIdx.x * 256 * 625;
    const int rem = Ntot - blockIdx.x * 256;           // >= 1 by grid sizing
    const int cmax = min(8, (rem + 31) >> 5);          // live chunks, block-uniform

    for (int c = 0; c < cmax; ++c) {
        const int ow = c >> 1;  // wave owning this chunk's scatter

        if (w == ow) {
            // scatter: owning 32 threads recompute D and stream into buf[c&1]
            if ((t >> 5) == c && gp < Ntot) {
                float* __restrict__ row = &buf[c & 1][p0 * 625];
                row[0] = 1.0f;  // l=0 block

                // R1 in real-SH l=1 basis order (y,z,x), row-major 3x3
                float D1[9] = {cp,      0.0f, -sp,
                               st * sp, ct,   st * cp,
                               ct * sp, -st,  ct * cp};
                write_l1(D1, row, std::make_index_sequence<9>{});

                float D2[25];
                level<T2, 2, true>(D1, D1, D2, row, std::make_index_sequence<25>{});
                float D3[49];
                level<T3, 3, true>(D1, D2, D3, row, std::make_index_sequence<49>{});
                level<T4, 4, false>(D1, D3, nullptr, row, std::make_index_sequence<81>{});
            }
        } else if (c > 0) {
            // copy chunk c-1 (always full: partial chunk is only ever cmax-1,
            // which is copied in the final phase below) by the 3 non-owner
            // waves: contiguous 16B v4f stream, 192-thread partition.
            const int w3 = w - (w > ow ? 1 : 0);       // rank among non-owner waves
            const int r = (w3 << 6) + lane;            // 0..191
            const v4f* __restrict__ src = (const v4f*)&buf[(c - 1) & 1][0];
            v4f* __restrict__ dst = (v4f*)(out + blk_f + (long long)(c - 1) * 32 * 625);
#pragma unroll 4
            for (int k = r; k < 5000; k += 192) dst[k] = src[k];
        }
        bar_lgkm();  // scatter visible; copy ds_reads retired (closes WAR)
    }

    // final copy: last chunk, all 256 threads
    {
        const int cl = cmax - 1;
        const int vpl = min(32, rem - cl * 32);
        const long long out_f = blk_f + (long long)cl * 32 * 625;
        if (vpl == 32) {
            const v4f* __restrict__ src = (const v4f*)&buf[cl & 1][0];
            v4f* __restrict__ dst = (v4f*)(out + out_f);
#pragma unroll 4
            for (int k = t; k < 5000; k += 256) dst[k] = src[k];
        } else {
            const int vf = vpl * 625;
            const float* __restrict__ src = &buf[cl & 1][0];
            for (int k = t; k < vf; k += 256) out[out_f + k] = src[k];
        }
    }
}

extern "C" void kernel_launch(void* const* d_in, const int* in_sizes, int n_in,
                              void* d_out, int out_size, void* d_ws, size_t ws_size,
                              hipStream_t stream) {
    const float* xyz = (const float*)d_in[0];
    float* out = (float*)d_out;
    const int N = in_sizes[0] / 3;
    const int blocks = (N + 255) / 256;
    hipLaunchKernelGGL(wigner_fused_kernel, dim3(blocks), dim3(256), 0, stream,
                       xyz, out, N);
}